// Round 2
// baseline (668.164 us; speedup 1.0000x reference)
//
#include <hip/hip_runtime.h>
#include <hip/hip_bf16.h>
#include <stdint.h>

typedef unsigned short u16;
typedef __attribute__((ext_vector_type(8))) short bf16x8;
typedef __attribute__((ext_vector_type(4))) float f32x4;

#define HEADS 8
#define DHEAD 128
#define NSEQ 1024
#define BATCH 4
#define DIM 1024
#define ATT_SCALE 0.088388347648318447f  // 1/sqrt(128)

static __device__ __forceinline__ float bf2f(u16 u){
  union { unsigned int i; float f; } c; c.i = ((unsigned int)u) << 16; return c.f;
}
static __device__ __forceinline__ u16 f2bf(float f){
  union { float f; unsigned int i; } c; c.f = f;
  unsigned int x = c.i;
  return (u16)((x + 0x7fffu + ((x >> 16) & 1u)) >> 16);
}

// ---------------- LayerNorm: fp32 in, bf16 out; one block per row of 1024 ----
__global__ __launch_bounds__(256)
void ln_kernel(const float* __restrict__ x, const float* __restrict__ w,
               const float* __restrict__ b, u16* __restrict__ out)
{
  const int row = blockIdx.x;
  const int t = threadIdx.x;
  const float* xr = x + (size_t)row * DIM;
  float4 v4 = *(const float4*)(xr + t*4);
  float v[4] = {v4.x, v4.y, v4.z, v4.w};
  float s = v[0]+v[1]+v[2]+v[3];
  __shared__ float red[256];
  red[t] = s; __syncthreads();
  for (int o=128;o;o>>=1){ if (t<o) red[t]+=red[t+o]; __syncthreads(); }
  const float mean = red[0] * (1.0f/DIM);
  __syncthreads();
  s = 0.f;
#pragma unroll
  for (int i=0;i<4;i++){ float d = v[i]-mean; s += d*d; }
  red[t] = s; __syncthreads();
  for (int o=128;o;o>>=1){ if (t<o) red[t]+=red[t+o]; __syncthreads(); }
  const float rstd = rsqrtf(red[0]*(1.0f/DIM) + 1e-5f);
  float4 w4 = *(const float4*)(w + t*4);
  float4 b4 = *(const float4*)(b + t*4);
  float wv[4] = {w4.x, w4.y, w4.z, w4.w};
  float bv[4] = {b4.x, b4.y, b4.z, b4.w};
  union { uint2 u; u16 s[4]; } ov;
#pragma unroll
  for (int i=0;i<4;i++)
    ov.s[i] = f2bf((v[i]-mean)*rstd*wv[i] + bv[i]);
  *(uint2*)(out + (size_t)row*DIM + t*4) = ov.u;
}

// ---------------- Generic MFMA GEMM ----------------
// C[M,N] = sum_k A[m,k] * B[k,n];  A bf16 K-major in <=3 segments of 1024 cols.
// B_F32ROWMAJOR=false: B is bf16 BT [N,K] row-major (K-major operand).
// B_F32ROWMAJOR=true:  B is fp32 [K,N] row-major, converted+transpose-staged.
// epi: 0 = bf16 C[z*cp + m*ldc + n] = val*alpha                (sim)
//      1 = bf16 head-merge: C[((z>>3)*N + m)*DIM + (z&7)*128 + n]  (out_pre)
//      2 = fp32 C[m*ldc+n] = val + bias[n]                     (final out)
//      3 = bf16 head-split: C[((m>>10)*8 + (n>>7))*1024*128 + (m&1023)*128 + (n&127)]
//      4 = fp32 head-merge                                     (context out)
template<bool B_F32ROWMAJOR>
__global__ __launch_bounds__(256)
void gemm_kernel(const u16* __restrict__ A0, const u16* __restrict__ A1,
                 const u16* __restrict__ A2, const void* __restrict__ Bv,
                 void* __restrict__ Cv, const float* __restrict__ bias,
                 int K, int lda, int ldb, int ldc,
                 long a_plane, long b_plane, long c_plane,
                 int epi, float alpha)
{
  __shared__ u16 sA[128*36];   // stride 36 elems (72B): <=2-way banks on b64 reads
  __shared__ u16 sB[128*36];
  const int t = threadIdx.x;
  const int m0 = blockIdx.y*128, n0 = blockIdx.x*128;
  const int z = blockIdx.z;
  const u16* A0p = A0 + (size_t)z*a_plane;
  const u16* A1p = A1 + (size_t)z*a_plane;
  const u16* A2p = A2 + (size_t)z*a_plane;

  const int wave = t>>6, lane = t&63;
  const int wm = (wave>>1)*64, wn = (wave&1)*64;
  const int lm = lane&15, q = lane>>4;

  const f32x4 zero4 = {0.f,0.f,0.f,0.f};
  f32x4 acc[4][4];
#pragma unroll
  for (int i=0;i<4;i++)
#pragma unroll
    for (int j=0;j<4;j++) acc[i][j] = zero4;

  const int arow = t>>2, ac8 = (t&3)*8;     // A staging: rows arow, arow+64; 8 cols
  const int bkp = t>>4, bc8 = (t&15)*8;     // B rowmajor staging: k-pair, 8 cols

  const int KT = K >> 5;
  for (int kt=0; kt<KT; ++kt){
    const int kg = kt<<5;
    const int seg = kg >> 10;
    const int ka = kg & 1023;
    const u16* Ap = (seg==0) ? A0p : (seg==1 ? A1p : A2p);
#pragma unroll
    for (int rr=0; rr<2; ++rr){
      const int row = arow + rr*64;
      union { uint4 v; uint2 h[2]; } av;
      av.v = *(const uint4*)(Ap + (size_t)(m0+row)*lda + (ka+ac8));
      *(uint2*)&sA[row*36 + ac8]     = av.h[0];
      *(uint2*)&sA[row*36 + ac8 + 4] = av.h[1];
    }
    if (!B_F32ROWMAJOR){
      const u16* Bp0 = (const u16*)Bv + (size_t)z*b_plane;
#pragma unroll
      for (int rr=0; rr<2; ++rr){
        const int row = arow + rr*64;
        union { uint4 v; uint2 h[2]; } bvv;
        bvv.v = *(const uint4*)(Bp0 + (size_t)(n0+row)*ldb + (kg+ac8));
        *(uint2*)&sB[row*36 + ac8]     = bvv.h[0];
        *(uint2*)&sB[row*36 + ac8 + 4] = bvv.h[1];
      }
    } else {
      // fp32 [K,N]: read 2 consecutive k-rows x 8 cols, convert, pack k-pairs
      const float* bp = (const float*)Bv + (size_t)(kg + bkp*2)*ldb + (n0 + bc8);
      float4 r0a = *(const float4*)bp;
      float4 r0b = *(const float4*)(bp + 4);
      float4 r1a = *(const float4*)(bp + ldb);
      float4 r1b = *(const float4*)(bp + ldb + 4);
      float k0v[8] = {r0a.x,r0a.y,r0a.z,r0a.w, r0b.x,r0b.y,r0b.z,r0b.w};
      float k1v[8] = {r1a.x,r1a.y,r1a.z,r1a.w, r1b.x,r1b.y,r1b.z,r1b.w};
#pragma unroll
      for (int e=0;e<8;e++){
        unsigned int d = (unsigned int)f2bf(k0v[e]) | ((unsigned int)f2bf(k1v[e]) << 16);
        *(unsigned int*)&sB[(bc8 + e)*36 + bkp*2] = d;
      }
    }
    __syncthreads();
    bf16x8 af[4], bfr[4];
#pragma unroll
    for (int f=0; f<4; ++f){
      const u16* pa = &sA[(wm + f*16 + lm)*36 + q*8];
      const u16* pb = &sB[(wn + f*16 + lm)*36 + q*8];
      union { bf16x8 v; uint2 h[2]; } ra, rb;
      ra.h[0] = *(const uint2*)pa; ra.h[1] = *(const uint2*)(pa+4);
      rb.h[0] = *(const uint2*)pb; rb.h[1] = *(const uint2*)(pb+4);
      af[f] = ra.v; bfr[f] = rb.v;
    }
#pragma unroll
    for (int fm=0; fm<4; ++fm)
#pragma unroll
      for (int fn=0; fn<4; ++fn)
        acc[fm][fn] = __builtin_amdgcn_mfma_f32_16x16x32_bf16(af[fm], bfr[fn], acc[fm][fn], 0, 0, 0);
    __syncthreads();
  }

#pragma unroll
  for (int fm=0; fm<4; ++fm){
#pragma unroll
    for (int fn=0; fn<4; ++fn){
#pragma unroll
      for (int r=0; r<4; ++r){
        const int m = m0 + wm + fm*16 + q*4 + r;
        const int n = n0 + wn + fn*16 + lm;
        float val = acc[fm][fn][r] * alpha;
        if (epi == 0){
          ((u16*)Cv)[(size_t)z*c_plane + (size_t)m*ldc + n] = f2bf(val);
        } else if (epi == 1){
          ((u16*)Cv)[((size_t)(z>>3)*NSEQ + m)*DIM + (size_t)(z&7)*DHEAD + n] = f2bf(val);
        } else if (epi == 2){
          ((float*)Cv)[(size_t)m*ldc + n] = val + bias[n];
        } else if (epi == 3){
          ((u16*)Cv)[(size_t)(((m>>10)*HEADS + (n>>7))*NSEQ + (m&1023))*DHEAD + (n&127)] = f2bf(val);
        } else {
          ((float*)Cv)[((size_t)(z>>3)*NSEQ + m)*DIM + (size_t)(z&7)*DHEAD + n] = val;
        }
      }
    }
  }
}

// ---------------- transpose [32][1024][128] -> [32][128][1024] (bf16) --------
__global__ __launch_bounds__(256)
void transpose_kernel(const u16* __restrict__ X, u16* __restrict__ XT)
{
  __shared__ u16 tile[32][33];
  const int z = blockIdx.z;
  const int i0 = blockIdx.y*32, d0 = blockIdx.x*32;
  const int t = threadIdx.x;
  const int tc = t & 31, tr = t >> 5;
  const u16* Xp = X + (size_t)z*NSEQ*DHEAD;
#pragma unroll
  for (int p=0;p<4;p++){
    int i = tr + p*8;
    tile[i][tc] = Xp[(size_t)(i0+i)*DHEAD + d0 + tc];
  }
  __syncthreads();
  u16* Op = XT + (size_t)z*DHEAD*NSEQ;
#pragma unroll
  for (int p=0;p<4;p++){
    int d = tr + p*8;
    Op[(size_t)(d0+d)*NSEQ + i0 + tc] = tile[tc][d];
  }
}

// ---------------- softmax stats ----------------
__global__ __launch_bounds__(256)
void row_stats_kernel(const u16* __restrict__ sim,
                      float* __restrict__ rmax, float* __restrict__ rrcp)
{
  const int wave = threadIdx.x >> 6, lane = threadIdx.x & 63;
  const int row = blockIdx.x*4 + wave;   // 0..32767 = (b*8+h)*1024+i
  const u16* sr = sim + (size_t)row * NSEQ;
  float v[16]; float m = -1e30f;
#pragma unroll
  for (int c=0;c<16;c++){ v[c] = bf2f(sr[lane + c*64]); m = fmaxf(m, v[c]); }
#pragma unroll
  for (int off=32; off; off>>=1) m = fmaxf(m, __shfl_xor(m, off));
  float s = 0.f;
#pragma unroll
  for (int c=0;c<16;c++) s += __expf(v[c]-m);
#pragma unroll
  for (int off=32; off; off>>=1) s += __shfl_xor(s, off);
  if (lane == 0){ rmax[row] = m; rrcp[row] = 1.0f/s; }
}

__global__ __launch_bounds__(256)
void col_stats_kernel(const u16* __restrict__ sim,
                      float* __restrict__ cmax, float* __restrict__ crcp)
{
  const int c = blockIdx.x*256 + threadIdx.x;  // (b*8+h)*1024 + j
  const int bh = c >> 10, j = c & 1023;
  const u16* sp = sim + (size_t)bh*NSEQ*NSEQ + j;
  float m = -1e30f, s = 0.f;
  for (int i=0;i<NSEQ;i++){
    float v = bf2f(sp[(size_t)i*NSEQ]);
    float nm = fmaxf(m, v);
    s = s*__expf(m-nm) + __expf(v-nm);
    m = nm;
  }
  cmax[c] = m; crcp[c] = 1.0f/s;
}

// ---------------- softmax + talking-heads mix ----------------
// IN-PLACE: am overwrites sim (per-thread read-before-write, same addresses).
// Also writes cmT[b,g,j,i] (transposed via LDS).
__global__ __launch_bounds__(256)
void mix_kernel(u16* simam,   // no __restrict__: read sim / write am, same buffer
                const float* __restrict__ rmax, const float* __restrict__ rrcp,
                const float* __restrict__ cmax, const float* __restrict__ crcp,
                const float* __restrict__ thw, const float* __restrict__ cthw,
                u16* __restrict__ cmT)
{
  __shared__ float s_th[64], s_cth[64];
  __shared__ u16 s_cm[8][32][33];
  const int t = threadIdx.x;
  if (t < 64){ s_th[t] = thw[t]; s_cth[t] = cthw[t]; }
  __syncthreads();
  const int b = blockIdx.z, i0 = blockIdx.y*32, j0 = blockIdx.x*32;
  const int tj = t & 31, ti = t >> 5;
  for (int p=0;p<4;p++){
    const int i = ti + p*8;
    float a[8], c[8];
#pragma unroll
    for (int h=0;h<8;h++){
      const int bh = b*8 + h;
      const float v = bf2f(simam[((size_t)bh*NSEQ + (i0+i))*NSEQ + j0 + tj]);
      a[h] = __expf(v - rmax[(size_t)bh*NSEQ + i0+i]) * rrcp[(size_t)bh*NSEQ + i0+i];
      c[h] = __expf(v - cmax[(size_t)bh*NSEQ + j0+tj]) * crcp[(size_t)bh*NSEQ + j0+tj];
    }
#pragma unroll
    for (int g=0;g<8;g++){
      float sa = 0.f, sc = 0.f;
#pragma unroll
      for (int h=0;h<8;h++){ sa += s_th[g*8+h]*a[h]; sc += s_cth[g*8+h]*c[h]; }
      simam[((size_t)(b*8+g)*NSEQ + (i0+i))*NSEQ + j0 + tj] = f2bf(sa);
      s_cm[g][i][tj] = f2bf(sc);
    }
  }
  __syncthreads();
#pragma unroll
  for (int g=0;g<8;g++){
#pragma unroll
    for (int p=0;p<4;p++){
      const int j = ti + p*8;
      cmT[((size_t)(b*8+g)*NSEQ + (j0+j))*NSEQ + i0 + tj] = s_cm[g][tj][j];
    }
  }
}

extern "C" void kernel_launch(void* const* d_in, const int* in_sizes, int n_in,
                              void* d_out, int out_size, void* d_ws, size_t ws_size,
                              hipStream_t stream)
{
  const float* x     = (const float*)d_in[0];
  const float* cinfo = (const float*)d_in[1];
  const float* ref   = (const float*)d_in[2];
  const float* ln_w  = (const float*)d_in[3];
  const float* ln_b  = (const float*)d_in[4];
  const float* cln_w = (const float*)d_in[5];
  const float* cln_b = (const float*)d_in[6];
  const float* Wk    = (const float*)d_in[7];
  const float* Wv    = (const float*)d_in[8];
  const float* Wo    = (const float*)d_in[9];
  const float* bo    = (const float*)d_in[10];
  const float* thw   = (const float*)d_in[11];
  const float* cthw  = (const float*)d_in[12];
  float* out = (float*)d_out;

  char* ws = (char*)d_ws;
  // bf16 workspace; total 184 MiB. Buffers reused once dead.
  u16* xn    = (u16*)(ws + 0);          // 8 MB; reused as out_pre
  u16* cn    = (u16*)(ws + 8388608);    // 8 MB; reused for softmax stats
  u16* rn    = (u16*)(ws + 16777216);   // 8 MB
  u16* cond  = (u16*)(ws + 25165824);   // 8 MB  [b,h,i,d]
  u16* refv  = (u16*)(ws + 33554432);   // 8 MB  [b,h,j,d]
  u16* condT = (u16*)(ws + 41943040);   // 8 MB  [b,h,d,j]
  u16* refvT = (u16*)(ws + 50331648);   // 8 MB  [b,h,d,j]
  u16* sim   = (u16*)(ws + 58720256);   // 64 MB [b,h,i,j]; becomes am in-place
  u16* cmT   = (u16*)(ws + 125829120);  // 64 MB [b,g,j,i]
  float* rmax = (float*)(ws + 8388608);
  float* rrcp = (float*)(ws + 8388608 + 131072);
  float* cmax = (float*)(ws + 8388608 + 262144);
  float* crcp = (float*)(ws + 8388608 + 393216);
  u16* out_pre = (u16*)(ws + 0);

  // 1) LayerNorms (fp32 -> bf16)
  ln_kernel<<<4096, 256, 0, stream>>>(x,     ln_w,  ln_b,  xn);
  ln_kernel<<<4096, 256, 0, stream>>>(ref,   ln_w,  ln_b,  rn);
  ln_kernel<<<4096, 256, 0, stream>>>(cinfo, cln_w, cln_b, cn);

  // 2) projections (fp32 B row-major, head-split epilogue)
  gemm_kernel<true><<<dim3(8,32,1), 256, 0, stream>>>(xn, cn, rn, Wk, cond, nullptr,
      3072, DIM, DIM, 0, 0, 0, 0, 3, 1.0f);
  gemm_kernel<true><<<dim3(8,32,1), 256, 0, stream>>>(xn, rn, rn, Wv, refv, nullptr,
      2048, DIM, DIM, 0, 0, 0, 0, 3, 1.0f);

  // 3) transposed copies for the PV/context GEMM B-operands
  transpose_kernel<<<dim3(4,32,32), 256, 0, stream>>>(cond, condT);
  transpose_kernel<<<dim3(4,32,32), 256, 0, stream>>>(refv, refvT);

  // 4) sim = cond @ refv^T * scale  (per (b,h) plane)
  gemm_kernel<false><<<dim3(8,8,32), 256, 0, stream>>>(cond, cond, cond, refv, sim, nullptr,
      DHEAD, DHEAD, DHEAD, NSEQ, (long)NSEQ*DHEAD, (long)NSEQ*DHEAD, (long)NSEQ*NSEQ, 0, ATT_SCALE);

  // 5) softmax stats
  row_stats_kernel<<<8192, 256, 0, stream>>>(sim, rmax, rrcp);
  col_stats_kernel<<<128, 256, 0, stream>>>(sim, cmax, crcp);

  // 6) both softmaxes + talking heads (am in-place over sim; cmT transposed)
  mix_kernel<<<dim3(32,32,4), 256, 0, stream>>>(sim, rmax, rrcp, cmax, crcp, thw, cthw, cmT);

  // 7) out_pre[b,i,g*128+d] = am @ refv ; context out = cmT @ cond (fp32 head-merge)
  gemm_kernel<false><<<dim3(1,8,32), 256, 0, stream>>>(sim, sim, sim, refvT, out_pre, nullptr,
      NSEQ, NSEQ, NSEQ, 0, (long)NSEQ*NSEQ, (long)DHEAD*NSEQ, 0, 1, 1.0f);
  gemm_kernel<false><<<dim3(1,8,32), 256, 0, stream>>>(cmT, cmT, cmT, condT,
      out + (size_t)BATCH*NSEQ*DIM, nullptr,
      NSEQ, NSEQ, NSEQ, 0, (long)NSEQ*NSEQ, (long)DHEAD*NSEQ, 0, 4, 1.0f);

  // 8) final projection: out = out_pre @ Wo + bo (fp32 out)
  gemm_kernel<true><<<dim3(8,32,1), 256, 0, stream>>>(out_pre, out_pre, out_pre, Wo, out, bo,
      DIM, DIM, DIM, DIM, 0, 0, 0, 2, 1.0f);
}

// Round 3
// 518.513 us; speedup vs baseline: 1.2886x; 1.2886x over previous
//
#include <hip/hip_runtime.h>
#include <hip/hip_bf16.h>
#include <stdint.h>

typedef unsigned short u16;
typedef __attribute__((ext_vector_type(8))) short bf16x8;
typedef __attribute__((ext_vector_type(4))) float f32x4;

#define HEADS 8
#define DHEAD 128
#define NSEQ 1024
#define BATCH 4
#define DIM 1024
#define ATT_SCALE 0.088388347648318447f  // 1/sqrt(128)

static __device__ __forceinline__ float bf2f(u16 u){
  union { unsigned int i; float f; } c; c.i = ((unsigned int)u) << 16; return c.f;
}
static __device__ __forceinline__ u16 f2bf(float f){
  union { float f; unsigned int i; } c; c.f = f;
  unsigned int x = c.i;
  return (u16)((x + 0x7fffu + ((x >> 16) & 1u)) >> 16);
}

// async global->LDS, 16B per lane, dest = wave-uniform base + lane*16
static __device__ __forceinline__ void gload_lds16(const void* g, void* l){
  __builtin_amdgcn_global_load_lds((__attribute__((address_space(1))) void*)(g),
                                   (__attribute__((address_space(3))) void*)(l),
                                   16, 0, 0);
}

// ---------------- LayerNorm: fp32 in, bf16 out; one block per row of 1024 ----
__global__ __launch_bounds__(256)
void ln_kernel(const float* __restrict__ x, const float* __restrict__ w,
               const float* __restrict__ b, u16* __restrict__ out)
{
  const int row = blockIdx.x;
  const int t = threadIdx.x;
  const float* xr = x + (size_t)row * DIM;
  float4 v4 = *(const float4*)(xr + t*4);
  float v[4] = {v4.x, v4.y, v4.z, v4.w};
  float s = v[0]+v[1]+v[2]+v[3];
  __shared__ float red[256];
  red[t] = s; __syncthreads();
  for (int o=128;o;o>>=1){ if (t<o) red[t]+=red[t+o]; __syncthreads(); }
  const float mean = red[0] * (1.0f/DIM);
  __syncthreads();
  s = 0.f;
#pragma unroll
  for (int i=0;i<4;i++){ float d = v[i]-mean; s += d*d; }
  red[t] = s; __syncthreads();
  for (int o=128;o;o>>=1){ if (t<o) red[t]+=red[t+o]; __syncthreads(); }
  const float rstd = rsqrtf(red[0]*(1.0f/DIM) + 1e-5f);
  float4 w4 = *(const float4*)(w + t*4);
  float4 b4 = *(const float4*)(b + t*4);
  float wv[4] = {w4.x, w4.y, w4.z, w4.w};
  float bv[4] = {b4.x, b4.y, b4.z, b4.w};
  union { uint2 u; u16 s[4]; } ov;
#pragma unroll
  for (int i=0;i<4;i++)
    ov.s[i] = f2bf((v[i]-mean)*rstd*wv[i] + bv[i]);
  *(uint2*)(out + (size_t)row*DIM + t*4) = ov.u;
}

// ---------------- MFMA GEMM, dbuf + global_load_lds, MFMA-ready LDS ---------
// C[M,N] = sum_k A[m,k]*B[k,n]. A bf16 K-major, <=3 segments of 1024 cols.
// Dual-problem: blockIdx.z >= z_split selects (A0b,A1b,Bv2,Cv2,epi2,K2).
// BF32=false: B is bf16 BT [N,K] row-major (K-major), staged via global_load_lds.
// BF32=true:  B is fp32 [K,N] row-major, reg-prefetch + convert + ds_write.
// LDS layout (per 128x32 tile, per buffer = 8KB): 8 blocks of 16 rows; block g,
// slot l (l=0..63, 16B each) holds elems [row=g*16+(l>>2)][k8=(l&3)*8 .. +7].
// Fragment (row=lm, k-oct=q) = slot lm*4+q -> one ds_read_b128, no conflicts.
// epi: 0 bf16 C[z*cp+m*ldc+n]*alpha | 1 bf16 head-merge | 2 fp32 +bias[n]
//      3 bf16 head-split | 4 fp32 head-merge
template<bool BF32>
__global__ __launch_bounds__(256)
void gemm_kernel(const u16* __restrict__ A0, const u16* __restrict__ A1,
                 const u16* __restrict__ A2, const u16* __restrict__ A0b,
                 const u16* __restrict__ A1b,
                 const void* __restrict__ Bv, const void* __restrict__ Bv2,
                 void* __restrict__ Cv, void* __restrict__ Cv2,
                 const float* __restrict__ bias,
                 int K1, int K2, int lda, int ldb, int ldc,
                 long a_plane, long b_plane, long c_plane,
                 int epi1, int epi2, int z_split, float alpha)
{
  __shared__ __attribute__((aligned(16))) u16 sA[2][4096];
  __shared__ __attribute__((aligned(16))) u16 sB[2][4096];
  const int t = threadIdx.x;
  const int m0 = blockIdx.y*128, n0 = blockIdx.x*128;
  const int zz = blockIdx.z;
  const bool side = (zz >= z_split);
  const int z = side ? (zz - z_split) : zz;
  const u16* a0 = (side ? A0b : A0) + (size_t)z*a_plane;
  const u16* a1 = (side ? A1b : A1) + (size_t)z*a_plane;
  const u16* a2 = A2 + (size_t)z*a_plane;
  const u16* bB = (const u16*)(side ? Bv2 : Bv) + (size_t)z*b_plane;
  const float* bF = (const float*)(side ? Bv2 : Bv);
  void* Cp = side ? Cv2 : Cv;
  const int EPI = side ? epi2 : epi1;
  const int K  = side ? K2 : K1;

  const int wave = t>>6, lane = t&63;
  const int wm = (wave>>1)*64, wn = (wave&1)*64;
  const int lm = lane&15, q = lane>>4;

  const f32x4 zero4 = {0.f,0.f,0.f,0.f};
  f32x4 acc[4][4];
#pragma unroll
  for (int i=0;i<4;i++)
#pragma unroll
    for (int j=0;j<4;j++) acc[i][j] = zero4;

  const int arowblk = wave*32;             // this wave stages row blocks arowblk, +16
  const int lrow = lane>>2, lk8 = (lane&3)*8;
  const int bkp = t>>4, bc8 = (t&15)*8;    // fp32-B staging: k-pair bkp*2, 8 n's
  float rN[16];

  const int KT = K >> 5;

  auto issueA = [&](int kt, int buf){
    const int kg = kt<<5, seg = kg>>10, ka = kg&1023;
    const u16* Ap = (seg==0) ? a0 : (seg==1 ? a1 : a2);
#pragma unroll
    for (int rr=0; rr<2; ++rr){
      const int rb = arowblk + rr*16;
      gload_lds16(Ap + (size_t)(m0+rb+lrow)*lda + (ka + lk8), &sA[buf][rb*32]);
    }
  };
  auto issueB16 = [&](int kt, int buf){
    const int kg = kt<<5;
#pragma unroll
    for (int rr=0; rr<2; ++rr){
      const int rb = arowblk + rr*16;
      gload_lds16(bB + (size_t)(n0+rb+lrow)*ldb + (kg + lk8), &sB[buf][rb*32]);
    }
  };
  auto loadBf32 = [&](int kt){
    const float* bp = bF + (size_t)((kt<<5) + bkp*2)*ldb + (n0 + bc8);
    float4 r0a = *(const float4*)bp;
    float4 r0b = *(const float4*)(bp + 4);
    float4 r1a = *(const float4*)(bp + ldb);
    float4 r1b = *(const float4*)(bp + ldb + 4);
    rN[0]=r0a.x; rN[1]=r0a.y; rN[2]=r0a.z; rN[3]=r0a.w;
    rN[4]=r0b.x; rN[5]=r0b.y; rN[6]=r0b.z; rN[7]=r0b.w;
    rN[8]=r1a.x; rN[9]=r1a.y; rN[10]=r1a.z; rN[11]=r1a.w;
    rN[12]=r1b.x; rN[13]=r1b.y; rN[14]=r1b.z; rN[15]=r1b.w;
  };
  auto writeBf32 = [&](int buf){
#pragma unroll
    for (int e=0;e<8;e++){
      unsigned int dw = (unsigned int)f2bf(rN[e]) | ((unsigned int)f2bf(rN[8+e]) << 16);
      const int n = bc8 + e;
      *(unsigned int*)&sB[buf][(n>>4)*512 + ((n&15)*4 + (bkp>>2))*8 + (bkp&3)*2] = dw;
    }
  };

  // prologue: stage tile 0 into buffer 0
  issueA(0, 0);
  if (BF32){ loadBf32(0); writeBf32(0); } else { issueB16(0, 0); }

  int cur = 0;
  for (int kt=0; kt<KT; ++kt){
    __syncthreads();                        // drains vmcnt/lgkm: buf[cur] ready
    const bool pf = (kt+1 < KT);
    if (pf){
      issueA(kt+1, cur^1);                  // async into other buffer
      if (BF32) loadBf32(kt+1); else issueB16(kt+1, cur^1);
    }
    bf16x8 af[4], bfr[4];
#pragma unroll
    for (int f=0; f<4; ++f){
      af[f]  = *(const bf16x8*)&sA[cur][((wm>>4)+f)*512 + (lm*4+q)*8];
      bfr[f] = *(const bf16x8*)&sB[cur][((wn>>4)+f)*512 + (lm*4+q)*8];
    }
#pragma unroll
    for (int fm=0; fm<4; ++fm)
#pragma unroll
      for (int fn=0; fn<4; ++fn)
        acc[fm][fn] = __builtin_amdgcn_mfma_f32_16x16x32_bf16(af[fm], bfr[fn], acc[fm][fn], 0, 0, 0);
    if (BF32 && pf) writeBf32(cur^1);       // fp32 load latency hidden behind MFMA
    cur ^= 1;
  }

#pragma unroll
  for (int fm=0; fm<4; ++fm){
#pragma unroll
    for (int fn=0; fn<4; ++fn){
#pragma unroll
      for (int r=0; r<4; ++r){
        const int m = m0 + wm + fm*16 + q*4 + r;
        const int n = n0 + wn + fn*16 + lm;
        float val = acc[fm][fn][r] * alpha;
        if (EPI == 0){
          ((u16*)Cp)[(size_t)z*c_plane + (size_t)m*ldc + n] = f2bf(val);
        } else if (EPI == 1){
          ((u16*)Cp)[((size_t)(z>>3)*NSEQ + m)*DIM + (size_t)(z&7)*DHEAD + n] = f2bf(val);
        } else if (EPI == 2){
          ((float*)Cp)[(size_t)m*ldc + n] = val + bias[n];
        } else if (EPI == 3){
          ((u16*)Cp)[(size_t)(((m>>10)*HEADS + (n>>7))*NSEQ + (m&1023))*DHEAD + (n&127)] = f2bf(val);
        } else {
          ((float*)Cp)[((size_t)(z>>3)*NSEQ + m)*DIM + (size_t)(z&7)*DHEAD + n] = val;
        }
      }
    }
  }
}

// ---------------- transpose [32][1024][128] -> [32][128][1024] (bf16) --------
__global__ __launch_bounds__(256)
void transpose_kernel(const u16* __restrict__ X, u16* __restrict__ XT)
{
  __shared__ u16 tile[32][33];
  const int z = blockIdx.z;
  const int i0 = blockIdx.y*32, d0 = blockIdx.x*32;
  const int t = threadIdx.x;
  const int tc = t & 31, tr = t >> 5;
  const u16* Xp = X + (size_t)z*NSEQ*DHEAD;
#pragma unroll
  for (int p=0;p<4;p++){
    int i = tr + p*8;
    tile[i][tc] = Xp[(size_t)(i0+i)*DHEAD + d0 + tc];
  }
  __syncthreads();
  u16* Op = XT + (size_t)z*DHEAD*NSEQ;
#pragma unroll
  for (int p=0;p<4;p++){
    int d = tr + p*8;
    Op[(size_t)(d0+d)*NSEQ + i0 + tc] = tile[tc][d];
  }
}

// ---------------- softmax stats ----------------
__global__ __launch_bounds__(256)
void row_stats_kernel(const u16* __restrict__ sim,
                      float* __restrict__ rmax, float* __restrict__ rrcp)
{
  const int wave = threadIdx.x >> 6, lane = threadIdx.x & 63;
  const int row = blockIdx.x*4 + wave;   // (b*8+h)*1024+i
  const u16* sr = sim + (size_t)row * NSEQ;
  float v[16]; float m = -1e30f;
#pragma unroll
  for (int c=0;c<16;c++){ v[c] = bf2f(sr[lane + c*64]); m = fmaxf(m, v[c]); }
#pragma unroll
  for (int off=32; off; off>>=1) m = fmaxf(m, __shfl_xor(m, off));
  float s = 0.f;
#pragma unroll
  for (int c=0;c<16;c++) s += __expf(v[c]-m);
#pragma unroll
  for (int off=32; off; off>>=1) s += __shfl_xor(s, off);
  if (lane == 0){ rmax[row] = m; rrcp[row] = 1.0f/s; }
}

// 4-way i-split column stats: 64 cols/block x 4 slices of 256 rows
__global__ __launch_bounds__(256)
void col_stats_kernel(const u16* __restrict__ sim,
                      float* __restrict__ cmax, float* __restrict__ crcp)
{
  __shared__ float smx[4][64], ssm[4][64];
  const int t = threadIdx.x;
  const int jl = t & 63, slice = t >> 6;
  const int c = blockIdx.x*64 + jl;      // (b*8+h)*1024 + j
  const int bh = c >> 10, j = c & 1023;
  const u16* sp = sim + (size_t)bh*NSEQ*NSEQ + j + (size_t)(slice*256)*NSEQ;
  float m = -1e30f, s = 0.f;
  for (int i=0;i<256;i++){
    float v = bf2f(sp[(size_t)i*NSEQ]);
    float nm = fmaxf(m, v);
    s = s*__expf(m-nm) + __expf(v-nm);
    m = nm;
  }
  smx[slice][jl] = m; ssm[slice][jl] = s;
  __syncthreads();
  if (slice == 0){
    float M = smx[0][jl];
#pragma unroll
    for (int p=1;p<4;p++) M = fmaxf(M, smx[p][jl]);
    float S = 0.f;
#pragma unroll
    for (int p=0;p<4;p++) S += ssm[p][jl]*__expf(smx[p][jl]-M);
    cmax[c] = M; crcp[c] = 1.0f/S;
  }
}

// ---------------- softmax + talking-heads mix ----------------
// IN-PLACE: am overwrites sim (per-thread read-before-write, same addresses).
// Also writes cmT[b,g,j,i] (transposed via LDS).
__global__ __launch_bounds__(256)
void mix_kernel(u16* simam,
                const float* __restrict__ rmax, const float* __restrict__ rrcp,
                const float* __restrict__ cmax, const float* __restrict__ crcp,
                const float* __restrict__ thw, const float* __restrict__ cthw,
                u16* __restrict__ cmT)
{
  __shared__ float s_th[64], s_cth[64];
  __shared__ u16 s_cm[8][32][33];
  const int t = threadIdx.x;
  if (t < 64){ s_th[t] = thw[t]; s_cth[t] = cthw[t]; }
  __syncthreads();
  const int b = blockIdx.z, i0 = blockIdx.y*32, j0 = blockIdx.x*32;
  const int tj = t & 31, ti = t >> 5;
  for (int p=0;p<4;p++){
    const int i = ti + p*8;
    float a[8], c[8];
#pragma unroll
    for (int h=0;h<8;h++){
      const int bh = b*8 + h;
      const float v = bf2f(simam[((size_t)bh*NSEQ + (i0+i))*NSEQ + j0 + tj]);
      a[h] = __expf(v - rmax[(size_t)bh*NSEQ + i0+i]) * rrcp[(size_t)bh*NSEQ + i0+i];
      c[h] = __expf(v - cmax[(size_t)bh*NSEQ + j0+tj]) * crcp[(size_t)bh*NSEQ + j0+tj];
    }
#pragma unroll
    for (int g=0;g<8;g++){
      float sa = 0.f, sc = 0.f;
#pragma unroll
      for (int h=0;h<8;h++){ sa += s_th[g*8+h]*a[h]; sc += s_cth[g*8+h]*c[h]; }
      simam[((size_t)(b*8+g)*NSEQ + (i0+i))*NSEQ + j0 + tj] = f2bf(sa);
      s_cm[g][i][tj] = f2bf(sc);
    }
  }
  __syncthreads();
#pragma unroll
  for (int g=0;g<8;g++){
#pragma unroll
    for (int p=0;p<4;p++){
      const int j = ti + p*8;
      cmT[((size_t)(b*8+g)*NSEQ + (j0+j))*NSEQ + i0 + tj] = s_cm[g][tj][j];
    }
  }
}

extern "C" void kernel_launch(void* const* d_in, const int* in_sizes, int n_in,
                              void* d_out, int out_size, void* d_ws, size_t ws_size,
                              hipStream_t stream)
{
  const float* x     = (const float*)d_in[0];
  const float* cinfo = (const float*)d_in[1];
  const float* ref   = (const float*)d_in[2];
  const float* ln_w  = (const float*)d_in[3];
  const float* ln_b  = (const float*)d_in[4];
  const float* cln_w = (const float*)d_in[5];
  const float* cln_b = (const float*)d_in[6];
  const float* Wk    = (const float*)d_in[7];
  const float* Wv    = (const float*)d_in[8];
  const float* Wo    = (const float*)d_in[9];
  const float* bo    = (const float*)d_in[10];
  const float* thw   = (const float*)d_in[11];
  const float* cthw  = (const float*)d_in[12];
  float* out = (float*)d_out;

  char* ws = (char*)d_ws;
  u16* xn    = (u16*)(ws + 0);          // 8 MB; reused as out_pre
  u16* cn    = (u16*)(ws + 8388608);    // 8 MB; reused for softmax stats
  u16* rn    = (u16*)(ws + 16777216);   // 8 MB
  u16* cond  = (u16*)(ws + 25165824);   // 8 MB  [b,h,i,d]
  u16* refv  = (u16*)(ws + 33554432);   // 8 MB  [b,h,j,d]
  u16* condT = (u16*)(ws + 41943040);   // 8 MB  [b,h,d,j]
  u16* refvT = (u16*)(ws + 50331648);   // 8 MB  [b,h,d,j]
  u16* sim   = (u16*)(ws + 58720256);   // 64 MB [b,h,i,j]; becomes am in-place
  u16* cmT   = (u16*)(ws + 125829120);  // 64 MB [b,g,j,i]
  float* rmax = (float*)(ws + 8388608);
  float* rrcp = (float*)(ws + 8388608 + 131072);
  float* cmax = (float*)(ws + 8388608 + 262144);
  float* crcp = (float*)(ws + 8388608 + 393216);
  u16* out_pre = (u16*)(ws + 0);

  // 1) LayerNorms (fp32 -> bf16)
  ln_kernel<<<4096, 256, 0, stream>>>(x,     ln_w,  ln_b,  xn);
  ln_kernel<<<4096, 256, 0, stream>>>(ref,   ln_w,  ln_b,  rn);
  ln_kernel<<<4096, 256, 0, stream>>>(cinfo, cln_w, cln_b, cn);

  // 2) fused projections: z=0 -> [xn|cn|rn]@Wk -> cond; z=1 -> [xn|rn]@Wv -> refv
  gemm_kernel<true><<<dim3(8,32,2), 256, 0, stream>>>(
      xn, cn, rn, xn, rn, Wk, Wv, cond, refv, nullptr,
      3072, 2048, DIM, DIM, 0, 0, 0, 0, 3, 3, 1, 1.0f);

  // 3) transposed copies for the PV/context GEMM B-operands
  transpose_kernel<<<dim3(4,32,32), 256, 0, stream>>>(cond, condT);
  transpose_kernel<<<dim3(4,32,32), 256, 0, stream>>>(refv, refvT);

  // 4) sim = cond @ refv^T * scale  (per (b,h) plane)
  gemm_kernel<false><<<dim3(8,8,32), 256, 0, stream>>>(
      cond, cond, cond, cond, cond, refv, refv, sim, sim, nullptr,
      DHEAD, DHEAD, DHEAD, DHEAD, NSEQ,
      (long)NSEQ*DHEAD, (long)NSEQ*DHEAD, (long)NSEQ*NSEQ, 0, 0, 1000000, ATT_SCALE);

  // 5) softmax stats
  row_stats_kernel<<<8192, 256, 0, stream>>>(sim, rmax, rrcp);
  col_stats_kernel<<<512, 256, 0, stream>>>(sim, cmax, crcp);

  // 6) both softmaxes + talking heads (am in-place over sim; cmT transposed)
  mix_kernel<<<dim3(32,32,4), 256, 0, stream>>>(sim, rmax, rrcp, cmax, crcp, thw, cthw, cmT);

  // 7) fused: z<32: am@refvT -> out_pre (bf16 head-merge); z>=32: cmT@condT -> ctx out (fp32)
  gemm_kernel<false><<<dim3(1,8,64), 256, 0, stream>>>(
      sim, sim, sim, cmT, cmT, refvT, condT, out_pre, out + (size_t)BATCH*NSEQ*DIM, nullptr,
      1024, 1024, NSEQ, NSEQ, 0,
      (long)NSEQ*NSEQ, (long)DHEAD*NSEQ, 0, 1, 4, 32, 1.0f);

  // 8) final projection: out = out_pre @ Wo + bo (fp32 out)
  gemm_kernel<true><<<dim3(8,32,1), 256, 0, stream>>>(
      out_pre, out_pre, out_pre, out_pre, out_pre, Wo, Wo, out, out, bo,
      1024, 1024, DIM, DIM, DIM, 0, 0, 0, 2, 2, 1000000, 1.0f);
}

// Round 4
// 472.820 us; speedup vs baseline: 1.4131x; 1.0966x over previous
//
#include <hip/hip_runtime.h>
#include <hip/hip_bf16.h>
#include <stdint.h>

typedef unsigned short u16;
typedef __attribute__((ext_vector_type(8))) short bf16x8;
typedef __attribute__((ext_vector_type(4))) float f32x4;

#define HEADS 8
#define DHEAD 128
#define NSEQ 1024
#define BATCH 4
#define DIM 1024
#define ATT_SCALE 0.088388347648318447f  // 1/sqrt(128)

static __device__ __forceinline__ float bf2f(u16 u){
  union { unsigned int i; float f; } c; c.i = ((unsigned int)u) << 16; return c.f;
}
static __device__ __forceinline__ u16 f2bf(float f){
  union { float f; unsigned int i; } c; c.f = f;
  unsigned int x = c.i;
  return (u16)((x + 0x7fffu + ((x >> 16) & 1u)) >> 16);
}

// async global->LDS, 16B per lane, dest = wave-uniform base + lane*16
static __device__ __forceinline__ void gload_lds16(const void* g, void* l){
  __builtin_amdgcn_global_load_lds((__attribute__((address_space(1))) void*)(g),
                                   (__attribute__((address_space(3))) void*)(l),
                                   16, 0, 0);
}

// ---------------- LayerNorm: fp32 in, bf16 out; one block per row of 1024 ----
__global__ __launch_bounds__(256)
void ln_kernel(const float* __restrict__ x, const float* __restrict__ w,
               const float* __restrict__ b, u16* __restrict__ out)
{
  const int row = blockIdx.x;
  const int t = threadIdx.x;
  const float* xr = x + (size_t)row * DIM;
  float4 v4 = *(const float4*)(xr + t*4);
  float v[4] = {v4.x, v4.y, v4.z, v4.w};
  float s = v[0]+v[1]+v[2]+v[3];
  __shared__ float red[256];
  red[t] = s; __syncthreads();
  for (int o=128;o;o>>=1){ if (t<o) red[t]+=red[t+o]; __syncthreads(); }
  const float mean = red[0] * (1.0f/DIM);
  __syncthreads();
  s = 0.f;
#pragma unroll
  for (int i=0;i<4;i++){ float d = v[i]-mean; s += d*d; }
  red[t] = s; __syncthreads();
  for (int o=128;o;o>>=1){ if (t<o) red[t]+=red[t+o]; __syncthreads(); }
  const float rstd = rsqrtf(red[0]*(1.0f/DIM) + 1e-5f);
  float4 w4 = *(const float4*)(w + t*4);
  float4 b4 = *(const float4*)(b + t*4);
  float wv[4] = {w4.x, w4.y, w4.z, w4.w};
  float bv[4] = {b4.x, b4.y, b4.z, b4.w};
  union { uint2 u; u16 s[4]; } ov;
#pragma unroll
  for (int i=0;i<4;i++)
    ov.s[i] = f2bf((v[i]-mean)*rstd*wv[i] + bv[i]);
  *(uint2*)(out + (size_t)row*DIM + t*4) = ov.u;
}

// -------- weight convert+transpose: fp32 [K,1024] -> bf16 [1024,K] ----------
__global__ __launch_bounds__(256)
void wcvt_kernel(const float* __restrict__ Wk, const float* __restrict__ Wv,
                 const float* __restrict__ Wo,
                 u16* __restrict__ WkT, u16* __restrict__ WvT, u16* __restrict__ WoT)
{
  const int z = blockIdx.z;
  const int K = (z==0) ? 3072 : (z==1) ? 2048 : 1024;
  if ((int)blockIdx.x*32 >= K) return;
  const float* W = (z==0) ? Wk : (z==1) ? Wv : Wo;
  u16* WT = (z==0) ? WkT : (z==1) ? WvT : WoT;
  __shared__ float tile[32][33];
  const int k0 = blockIdx.x*32, n0 = blockIdx.y*32;
  const int t = threadIdx.x, tc = t&31, tr = t>>5;
#pragma unroll
  for (int p=0;p<4;p++)
    tile[tr+p*8][tc] = W[(size_t)(k0+tr+p*8)*DIM + n0+tc];
  __syncthreads();
#pragma unroll
  for (int p=0;p<4;p++)
    WT[(size_t)(n0+tr+p*8)*K + k0+tc] = f2bf(tile[tc][tr+p*8]);
}

// ---------------- MFMA GEMM: dbuf + global_load_lds, conflict-free LDS ------
// C[M,N] = sum_k A[m,k]*B[k,n]. A bf16 K-major, <=3 segments of 1024 cols.
// B is bf16 BT [N,K] row-major (K-major operand). Dual-problem via z_split.
// LDS: per 128x32 tile (8KB/buf), 8 blocks of 16 rows; slot l (16B) of block g
// holds [row = g*16 + (l&15)][k-oct = l>>4]. Staged by gload_lds16 with lane l
// fetching global [row=l&15][oct=l>>4]  ->  fragment read = ds_read_b128 at
// base + lane*16: consecutive lanes -> consecutive banks, ZERO conflicts.
// epi: 0 bf16 C[z*cp+m*ldc+n]*alpha | 1 bf16 head-merge | 2 fp32 +bias[n]
//      3 bf16 head-split | 4 fp32 head-merge
__global__ __launch_bounds__(256)
void gemm_kernel(const u16* __restrict__ A0, const u16* __restrict__ A1,
                 const u16* __restrict__ A2, const u16* __restrict__ A0b,
                 const u16* __restrict__ A1b,
                 const u16* __restrict__ B1, const u16* __restrict__ B2,
                 void* __restrict__ Cv, void* __restrict__ Cv2,
                 const float* __restrict__ bias,
                 int K1, int K2, int lda, int ldb1, int ldb2, int ldc,
                 long a_plane, long b_plane, long c_plane,
                 int epi1, int epi2, int z_split, float alpha)
{
  __shared__ __attribute__((aligned(16))) u16 sA[2][4096];
  __shared__ __attribute__((aligned(16))) u16 sB[2][4096];
  const int t = threadIdx.x;
  const int m0 = blockIdx.y*128, n0 = blockIdx.x*128;
  const int zz = blockIdx.z;
  const bool side = (zz >= z_split);
  const int z = side ? (zz - z_split) : zz;
  const u16* a0 = (side ? A0b : A0) + (size_t)z*a_plane;
  const u16* a1 = (side ? A1b : A1) + (size_t)z*a_plane;
  const u16* a2 = A2 + (size_t)z*a_plane;
  const u16* bB = (side ? B2 : B1) + (size_t)z*b_plane;
  void* Cp = side ? Cv2 : Cv;
  const int EPI = side ? epi2 : epi1;
  const int K   = side ? K2 : K1;
  const int ldb = side ? ldb2 : ldb1;

  const int wave = t>>6, lane = t&63;
  const int wm = (wave>>1)*64, wn = (wave&1)*64;
  const int lm = lane&15, q = lane>>4;

  const f32x4 zero4 = {0.f,0.f,0.f,0.f};
  f32x4 acc[4][4];
#pragma unroll
  for (int i=0;i<4;i++)
#pragma unroll
    for (int j=0;j<4;j++) acc[i][j] = zero4;

  const int arowblk = wave*32;       // this wave stages 16-row blocks arowblk, +16

  const int KT = K >> 5;

  auto issueA = [&](int kt, int buf){
    const int kg = kt<<5, seg = kg>>10, ka = kg&1023;
    const u16* Ap = (seg==0) ? a0 : (seg==1 ? a1 : a2);
#pragma unroll
    for (int rr=0; rr<2; ++rr){
      const int rb = arowblk + rr*16;
      gload_lds16(Ap + (size_t)(m0+rb+lm)*lda + (ka + q*8), &sA[buf][rb*32]);
    }
  };
  auto issueB = [&](int kt, int buf){
    const int kg = kt<<5;
#pragma unroll
    for (int rr=0; rr<2; ++rr){
      const int rb = arowblk + rr*16;
      gload_lds16(bB + (size_t)(n0+rb+lm)*ldb + (kg + q*8), &sB[buf][rb*32]);
    }
  };

  // prologue: stage tile 0 into buffer 0
  issueA(0, 0);
  issueB(0, 0);

  int cur = 0;
  for (int kt=0; kt<KT; ++kt){
    __syncthreads();                        // drains vmcnt: buf[cur] ready
    if (kt+1 < KT){
      issueA(kt+1, cur^1);                  // async into other buffer
      issueB(kt+1, cur^1);
    }
    bf16x8 af[4], bfr[4];
#pragma unroll
    for (int f=0; f<4; ++f){
      af[f]  = *(const bf16x8*)&sA[cur][((wm>>4)+f)*512 + lane*8];
      bfr[f] = *(const bf16x8*)&sB[cur][((wn>>4)+f)*512 + lane*8];
    }
#pragma unroll
    for (int fm=0; fm<4; ++fm)
#pragma unroll
      for (int fn=0; fn<4; ++fn)
        acc[fm][fn] = __builtin_amdgcn_mfma_f32_16x16x32_bf16(af[fm], bfr[fn], acc[fm][fn], 0, 0, 0);
    cur ^= 1;
  }

#pragma unroll
  for (int fm=0; fm<4; ++fm){
#pragma unroll
    for (int fn=0; fn<4; ++fn){
#pragma unroll
      for (int r=0; r<4; ++r){
        const int m = m0 + wm + fm*16 + q*4 + r;
        const int n = n0 + wn + fn*16 + lm;
        float val = acc[fm][fn][r] * alpha;
        if (EPI == 0){
          ((u16*)Cp)[(size_t)z*c_plane + (size_t)m*ldc + n] = f2bf(val);
        } else if (EPI == 1){
          ((u16*)Cp)[((size_t)(z>>3)*NSEQ + m)*DIM + (size_t)(z&7)*DHEAD + n] = f2bf(val);
        } else if (EPI == 2){
          ((float*)Cp)[(size_t)m*ldc + n] = val + bias[n];
        } else if (EPI == 3){
          ((u16*)Cp)[(size_t)(((m>>10)*HEADS + (n>>7))*NSEQ + (m&1023))*DHEAD + (n&127)] = f2bf(val);
        } else {
          ((float*)Cp)[((size_t)(z>>3)*NSEQ + m)*DIM + (size_t)(z&7)*DHEAD + n] = val;
        }
      }
    }
  }
}

// ---------------- transpose [32][1024][128] -> [32][128][1024] (bf16) --------
__global__ __launch_bounds__(256)
void transpose_kernel(const u16* __restrict__ X, u16* __restrict__ XT)
{
  __shared__ u16 tile[32][33];
  const int z = blockIdx.z;
  const int i0 = blockIdx.y*32, d0 = blockIdx.x*32;
  const int t = threadIdx.x;
  const int tc = t & 31, tr = t >> 5;
  const u16* Xp = X + (size_t)z*NSEQ*DHEAD;
#pragma unroll
  for (int p=0;p<4;p++){
    int i = tr + p*8;
    tile[i][tc] = Xp[(size_t)(i0+i)*DHEAD + d0 + tc];
  }
  __syncthreads();
  u16* Op = XT + (size_t)z*DHEAD*NSEQ;
#pragma unroll
  for (int p=0;p<4;p++){
    int d = tr + p*8;
    Op[(size_t)(d0+d)*NSEQ + i0 + tc] = tile[tc][d];
  }
}

// ---------------- softmax stats ----------------
__global__ __launch_bounds__(256)
void row_stats_kernel(const u16* __restrict__ sim,
                      float* __restrict__ rmax, float* __restrict__ rrcp)
{
  const int wave = threadIdx.x >> 6, lane = threadIdx.x & 63;
  const int row = blockIdx.x*4 + wave;   // (b*8+h)*1024+i
  const u16* sr = sim + (size_t)row * NSEQ;
  float v[16]; float m = -1e30f;
#pragma unroll
  for (int c=0;c<16;c++){ v[c] = bf2f(sr[lane + c*64]); m = fmaxf(m, v[c]); }
#pragma unroll
  for (int off=32; off; off>>=1) m = fmaxf(m, __shfl_xor(m, off));
  float s = 0.f;
#pragma unroll
  for (int c=0;c<16;c++) s += __expf(v[c]-m);
#pragma unroll
  for (int off=32; off; off>>=1) s += __shfl_xor(s, off);
  if (lane == 0){ rmax[row] = m; rrcp[row] = 1.0f/s; }
}

// 4-way i-split column stats: 64 cols/block x 4 slices of 256 rows
__global__ __launch_bounds__(256)
void col_stats_kernel(const u16* __restrict__ sim,
                      float* __restrict__ cmax, float* __restrict__ crcp)
{
  __shared__ float smx[4][64], ssm[4][64];
  const int t = threadIdx.x;
  const int jl = t & 63, slice = t >> 6;
  const int c = blockIdx.x*64 + jl;      // (b*8+h)*1024 + j
  const int bh = c >> 10, j = c & 1023;
  const u16* sp = sim + (size_t)bh*NSEQ*NSEQ + j + (size_t)(slice*256)*NSEQ;
  float m = -1e30f, s = 0.f;
  for (int i=0;i<256;i++){
    float v = bf2f(sp[(size_t)i*NSEQ]);
    float nm = fmaxf(m, v);
    s = s*__expf(m-nm) + __expf(v-nm);
    m = nm;
  }
  smx[slice][jl] = m; ssm[slice][jl] = s;
  __syncthreads();
  if (slice == 0){
    float M = smx[0][jl];
#pragma unroll
    for (int p=1;p<4;p++) M = fmaxf(M, smx[p][jl]);
    float S = 0.f;
#pragma unroll
    for (int p=0;p<4;p++) S += ssm[p][jl]*__expf(smx[p][jl]-M);
    cmax[c] = M; crcp[c] = 1.0f/S;
  }
}

// ---------------- softmax + talking-heads mix ----------------
// IN-PLACE: am overwrites sim (per-thread read-before-write, same addresses).
// Also writes cmT[b,g,j,i] (transposed via LDS).
__global__ __launch_bounds__(256)
void mix_kernel(u16* simam,
                const float* __restrict__ rmax, const float* __restrict__ rrcp,
                const float* __restrict__ cmax, const float* __restrict__ crcp,
                const float* __restrict__ thw, const float* __restrict__ cthw,
                u16* __restrict__ cmT)
{
  __shared__ float s_th[64], s_cth[64];
  __shared__ u16 s_cm[8][32][33];
  const int t = threadIdx.x;
  if (t < 64){ s_th[t] = thw[t]; s_cth[t] = cthw[t]; }
  __syncthreads();
  const int b = blockIdx.z, i0 = blockIdx.y*32, j0 = blockIdx.x*32;
  const int tj = t & 31, ti = t >> 5;
  for (int p=0;p<4;p++){
    const int i = ti + p*8;
    float a[8], c[8];
#pragma unroll
    for (int h=0;h<8;h++){
      const int bh = b*8 + h;
      const float v = bf2f(simam[((size_t)bh*NSEQ + (i0+i))*NSEQ + j0 + tj]);
      a[h] = __expf(v - rmax[(size_t)bh*NSEQ + i0+i]) * rrcp[(size_t)bh*NSEQ + i0+i];
      c[h] = __expf(v - cmax[(size_t)bh*NSEQ + j0+tj]) * crcp[(size_t)bh*NSEQ + j0+tj];
    }
#pragma unroll
    for (int g=0;g<8;g++){
      float sa = 0.f, sc = 0.f;
#pragma unroll
      for (int h=0;h<8;h++){ sa += s_th[g*8+h]*a[h]; sc += s_cth[g*8+h]*c[h]; }
      simam[((size_t)(b*8+g)*NSEQ + (i0+i))*NSEQ + j0 + tj] = f2bf(sa);
      s_cm[g][i][tj] = f2bf(sc);
    }
  }
  __syncthreads();
#pragma unroll
  for (int g=0;g<8;g++){
#pragma unroll
    for (int p=0;p<4;p++){
      const int j = ti + p*8;
      cmT[((size_t)(b*8+g)*NSEQ + (j0+j))*NSEQ + i0 + tj] = s_cm[g][tj][j];
    }
  }
}

extern "C" void kernel_launch(void* const* d_in, const int* in_sizes, int n_in,
                              void* d_out, int out_size, void* d_ws, size_t ws_size,
                              hipStream_t stream)
{
  const float* x     = (const float*)d_in[0];
  const float* cinfo = (const float*)d_in[1];
  const float* ref   = (const float*)d_in[2];
  const float* ln_w  = (const float*)d_in[3];
  const float* ln_b  = (const float*)d_in[4];
  const float* cln_w = (const float*)d_in[5];
  const float* cln_b = (const float*)d_in[6];
  const float* Wk    = (const float*)d_in[7];
  const float* Wv    = (const float*)d_in[8];
  const float* Wo    = (const float*)d_in[9];
  const float* bo    = (const float*)d_in[10];
  const float* thw   = (const float*)d_in[11];
  const float* cthw  = (const float*)d_in[12];
  float* out = (float*)d_out;

  char* ws = (char*)d_ws;
  u16* xn    = (u16*)(ws + 0);          // 8 MB; reused as out_pre
  u16* cn    = (u16*)(ws + 8388608);    // 8 MB; reused for softmax stats
  u16* rn    = (u16*)(ws + 16777216);   // 8 MB
  u16* cond  = (u16*)(ws + 25165824);   // 8 MB  [b,h,i,d]
  u16* refv  = (u16*)(ws + 33554432);   // 8 MB  [b,h,j,d]
  u16* condT = (u16*)(ws + 41943040);   // 8 MB  [b,h,d,j]
  u16* refvT = (u16*)(ws + 50331648);   // 8 MB  [b,h,d,j]
  u16* sim   = (u16*)(ws + 58720256);   // 64 MB [b,h,i,j]; becomes am in-place
  u16* cmT   = (u16*)(ws + 125829120);  // 64 MB [b,g,j,i]
  u16* WkT   = (u16*)(ws + 192937984);  // 6 MB  [1024,3072] bf16
  u16* WvT   = (u16*)(ws + 199229440);  // 4 MB  [1024,2048] bf16
  u16* WoT   = (u16*)(ws + 203423744);  // 2 MB  [1024,1024] bf16
  float* rmax = (float*)(ws + 8388608);
  float* rrcp = (float*)(ws + 8388608 + 131072);
  float* cmax = (float*)(ws + 8388608 + 262144);
  float* crcp = (float*)(ws + 8388608 + 393216);
  u16* out_pre = (u16*)(ws + 0);

  // 1) LayerNorms (fp32 -> bf16)
  ln_kernel<<<4096, 256, 0, stream>>>(x,     ln_w,  ln_b,  xn);
  ln_kernel<<<4096, 256, 0, stream>>>(ref,   ln_w,  ln_b,  rn);
  ln_kernel<<<4096, 256, 0, stream>>>(cinfo, cln_w, cln_b, cn);

  // 1b) weight convert+transpose fp32[K,N] -> bf16[N,K]
  wcvt_kernel<<<dim3(96,32,3), 256, 0, stream>>>(Wk, Wv, Wo, WkT, WvT, WoT);

  // 2) fused projections: z=0 -> [xn|cn|rn]@Wk -> cond; z=1 -> [xn|rn]@Wv -> refv
  gemm_kernel<<<dim3(8,32,2), 256, 0, stream>>>(
      xn, cn, rn, xn, rn, WkT, WvT, cond, refv, nullptr,
      3072, 2048, DIM, 3072, 2048, 0, 0, 0, 0, 3, 3, 1, 1.0f);

  // 3) transposed copies for the PV/context GEMM B-operands
  transpose_kernel<<<dim3(4,32,32), 256, 0, stream>>>(cond, condT);
  transpose_kernel<<<dim3(4,32,32), 256, 0, stream>>>(refv, refvT);

  // 4) sim = cond @ refv^T * scale  (per (b,h) plane)
  gemm_kernel<<<dim3(8,8,32), 256, 0, stream>>>(
      cond, cond, cond, cond, cond, refv, refv, sim, sim, nullptr,
      DHEAD, DHEAD, DHEAD, DHEAD, DHEAD, NSEQ,
      (long)NSEQ*DHEAD, (long)NSEQ*DHEAD, (long)NSEQ*NSEQ, 0, 0, 1000000, ATT_SCALE);

  // 5) softmax stats
  row_stats_kernel<<<8192, 256, 0, stream>>>(sim, rmax, rrcp);
  col_stats_kernel<<<512, 256, 0, stream>>>(sim, cmax, crcp);

  // 6) both softmaxes + talking heads (am in-place over sim; cmT transposed)
  mix_kernel<<<dim3(32,32,4), 256, 0, stream>>>(sim, rmax, rrcp, cmax, crcp, thw, cthw, cmT);

  // 7) fused: z<32: am@refvT -> out_pre (bf16 head-merge); z>=32: cmT@condT -> ctx out (fp32)
  gemm_kernel<<<dim3(1,8,64), 256, 0, stream>>>(
      sim, sim, sim, cmT, cmT, refvT, condT, out_pre, out + (size_t)BATCH*NSEQ*DIM, nullptr,
      1024, 1024, NSEQ, NSEQ, NSEQ, 0,
      (long)NSEQ*NSEQ, (long)DHEAD*NSEQ, 0, 1, 4, 32, 1.0f);

  // 8) final projection: out = out_pre @ Wo + bo (fp32 out)
  gemm_kernel<<<dim3(8,32,1), 256, 0, stream>>>(
      out_pre, out_pre, out_pre, out_pre, out_pre, WoT, WoT, out, out, bo,
      1024, 1024, DIM, 1024, 1024, DIM, 0, 0, 0, 2, 2, 1000000, 1.0f);
}